// Round 9
// baseline (2386.670 us; speedup 1.0000x reference)
//
#include <hip/hip_runtime.h>
#include <math.h>

// Problem constants (B,C,L,K) = (32, 64, 4096, 512)
#define B_DIM 32
#define C_DIM 64
#define L_DIM 4096
#define K_CB  512
#define N_ROWS (B_DIM * L_DIM)            // 131072
#define Q_ELEMS (B_DIM * C_DIM * L_DIM)   // 8388608

// Output layout (float32, concatenated in return order):
// loss(1), quantized_st(B,C,L), perplexity(1), embed(K,C), indices(B,L), encodings(N,K)
#define OFF_LOSS  0
#define OFF_Q     1
#define OFF_PERP  (1 + Q_ELEMS)
#define OFF_EMBED (OFF_PERP + 1)
#define OFF_IDX   (OFF_EMBED + K_CB * C_DIM)
#define OFF_ENC   (OFF_IDX + N_ROWS)

#define TPB     128   // threads per block (2 waves)
#define RPB     256   // rows per block (2 per thread)
#define KHALF   256   // codewords per K-half
#define KCHUNK  128   // codewords per LDS chunk (2 chunks per half)

using f4 = __attribute__((ext_vector_type(4))) float;
using f2 = __attribute__((ext_vector_type(2))) float;

// ws layout: [0:8) double loss; [16:16+2048) int hist[512]; [4096:+2048) float esq[512]

__global__ void vq_init(const float* __restrict__ embed,
                        double* __restrict__ loss_ws,
                        int* __restrict__ hist,
                        float* __restrict__ esq,
                        float* __restrict__ out_embed) {
  const int t = threadIdx.x;  // 512 threads, 1 block
  if (t == 0) *loss_ws = 0.0;
  hist[t] = 0;
  const float* row = embed + (size_t)t * C_DIM;
  float s = 0.f;
#pragma unroll
  for (int c = 0; c < C_DIM; ++c) s = fmaf(row[c], row[c], s);
  esq[t] = s;
#pragma unroll
  for (int i = 0; i < K_CB * C_DIM / 512; ++i)
    out_embed[i * 512 + t] = embed[i * 512 + t];
}

// ---------------------------------------------------------------------------
// Split-K distance GEMM. Block = (row-block rb, K-half kh): 256 rows x 256
// codewords. x in registers (f2 x 64); e broadcast from LDS (wave-uniform
// reads -> no bank traffic).
// KEY COMPILER CONTROLS:
//  - `in`/`out` are NON-const NON-restrict: enc stores may alias `in`, so
//    rematerializing x loads inside the loop is illegal -> x stays in VGPRs
//    (R6/R8 failed because the compiler demoted reg arrays to cache re-reads).
//  - amdgpu_waves_per_eu(2,2): VGPR budget 256 (need ~200), occupancy target
//    matches the 2048-wave grid (2 waves/SIMD). R7's launch_bounds(,2) capped
//    VGPRs at 128 and spilled to scratch (3.3 GB of FETCH).
// ---------------------------------------------------------------------------
__global__ __launch_bounds__(TPB) __attribute__((amdgpu_waves_per_eu(2, 2)))
void vq_gemm(float* in, const float* __restrict__ embed,
             const float* __restrict__ esq_g, float* out) {
  __shared__ float eT[KCHUNK * C_DIM];  // 32 KB, linear [k][c]
  __shared__ float esq_s[KCHUNK];

  const int tid = threadIdx.x;
  const int blk = blockIdx.x;            // 1024 blocks
  const int kh  = blk & 1;               // K-half (paired blocks share rows)
  const int rb  = blk >> 1;              // 0..511 row-block
  const int b   = rb >> 4;
  const int l0  = (rb & 15) * RPB;
  const int l   = l0 + 2 * tid;          // rows l, l+1 owned by this thread

  // --- load 2 x-rows into registers (f2, coalesced 8B/lane) ---
  const float* xp = in + (size_t)b * (C_DIM * L_DIM) + l;
  f2 x[C_DIM];
#pragma unroll
  for (int c = 0; c < C_DIM; ++c) x[c] = *(const f2*)(xp + (size_t)c * L_DIM);

  // flat_sq: sequential fmaf chain ascending c (bit-matches prior rounds)
  float fs0 = 0.f, fs1 = 0.f;
#pragma unroll
  for (int c = 0; c < C_DIM; ++c) {
    fs0 = fmaf(x[c].x, x[c].x, fs0);
    fs1 = fmaf(x[c].y, x[c].y, fs1);
  }

  f2* encb = (f2*)(out + OFF_ENC) + (size_t)rb * RPB * (K_CB / 2);
  f2 zz; zz.x = 0.f; zz.y = 0.f;

  float rmin0 = 3.402823466e38f, rmin1 = 3.402823466e38f;
  int   ridx0 = 0, ridx1 = 0;

  for (int ch = 0; ch < KHALF / KCHUNK; ++ch) {
    const int k0 = kh * KHALF + ch * KCHUNK;
    __syncthreads();  // previous chunk's readers done
    // Stage e chunk linear (coalesced f4): 8192 floats = 16 x 128thr x f4
#pragma unroll
    for (int i = 0; i < 16; ++i) {
      const int o = i * 512 + tid * 4;
      *(f4*)&eT[o] = *(const f4*)(embed + (size_t)k0 * C_DIM + o);
    }
    esq_s[tid] = esq_g[k0 + tid];
    __syncthreads();

    for (int kk = 0; kk < KCHUNK; kk += 8) {   // 16 groups of 8 codewords
      float a0[8], a1[8];
#pragma unroll
      for (int j = 0; j < 8; ++j) { a0[j] = 0.f; a1[j] = 0.f; }
#pragma unroll
      for (int cq = 0; cq < 16; ++cq) {        // c in quads, ascending
        f4 ev[8];
#pragma unroll
        for (int j = 0; j < 8; ++j)
          ev[j] = *(const f4*)&eT[(kk + j) * C_DIM + cq * 4];  // uniform -> broadcast
#pragma unroll
        for (int q = 0; q < 4; ++q) {
          const f2 xv = x[cq * 4 + q];
#pragma unroll
          for (int j = 0; j < 8; ++j) {
            a0[j] = fmaf(xv.x, ev[j][q], a0[j]);
            a1[j] = fmaf(xv.y, ev[j][q], a1[j]);
          }
        }
      }
      // enc zero-fill slice: coalesced 1KB nt-stores overlapping HBM under
      // compute (this K-half's columns only; f2 slots 0,1 hold candidates).
      {
        const int g = ch * 16 + (kk >> 3);  // 0..31
#pragma unroll
        for (int s = 0; s < 8; ++s) {
          const int row = g * 8 + s;
          if (!(kh == 0 && tid < 2))
            __builtin_nontemporal_store(
                zz, encb + (size_t)row * (K_CB / 2) + kh * (K_CB / 4) + tid);
        }
      }
      // min-update, ascending k, strict < : first-minimum semantics
#pragma unroll
      for (int j = 0; j < 8; ++j) {
        const int k = k0 + kk + j;
        const float es = esq_s[kk + j];
        const float d0 = fmaf(-2.0f, a0[j], fs0 + es);
        if (d0 < rmin0) { rmin0 = d0; ridx0 = k; }
        const float d1 = fmaf(-2.0f, a1[j], fs1 + es);
        if (d1 < rmin1) { rmin1 = d1; ridx1 = k; }
      }
    }
  }

  // --- candidate stores: f2 {min, idx} at row's enc f2-slot kh ---
  {
    f2 c0; c0.x = rmin0; c0.y = (float)ridx0;
    f2 c1; c1.x = rmin1; c1.y = (float)ridx1;
    encb[(size_t)(2 * tid)     * (K_CB / 2) + kh] = c0;
    encb[(size_t)(2 * tid + 1) * (K_CB / 2) + kh] = c1;
  }
}

// ---------------------------------------------------------------------------
// Merge candidates + idx + hist + enc-fix + quantized_st + loss.
// One thread per row (coalesced: lane = consecutive l).
// ---------------------------------------------------------------------------
__global__ __launch_bounds__(256) void vq_epilogue(
    const float* __restrict__ in, const float* __restrict__ embed,
    int* __restrict__ hist, double* __restrict__ loss_ws,
    float* __restrict__ out) {
  __shared__ double red[256];
  const int tid = threadIdx.x;
  const int r = blockIdx.x * 256 + tid;  // 0..131071 (== b*L + l)
  const int b = r >> 12;
  const int l = r & (L_DIM - 1);

  float* encrow = out + OFF_ENC + (size_t)r * K_CB;
  const f2 ca = ((const f2*)encrow)[0];  // {d_half0, k_half0}
  const f2 cb = ((const f2*)encrow)[1];  // {d_half1, k_half1}
  // strict <: half0 (lower k) wins ties -> global first-minimum
  const int k = (cb.x < ca.x) ? (int)cb.y : (int)ca.y;

  out[OFF_IDX + r] = (float)k;
  atomicAdd(&hist[k], 1);

  // fix enc scratch slots, then set the one-hot (same-address order is
  // per-thread program order, so k<4 is safe)
  f2 zz; zz.x = 0.f; zz.y = 0.f;
  ((f2*)encrow)[0] = zz;
  ((f2*)encrow)[1] = zz;
  encrow[k] = 1.0f;

  // quantized_st + loss
  const float* ep = embed + (size_t)k * C_DIM;   // L1/L2-resident gather
  const float* xp = in + (size_t)b * (C_DIM * L_DIM) + l;
  float* qp = out + OFF_Q + (size_t)b * (C_DIM * L_DIM) + l;
  double ls = 0.0;
#pragma unroll
  for (int c = 0; c < C_DIM; ++c) {
    const float xv = xp[(size_t)c * L_DIM];
    const float d = ep[c] - xv;                  // fp32, as reference
    __builtin_nontemporal_store(xv + d, qp + (size_t)c * L_DIM);
    ls += (double)(d * d);
  }

  red[tid] = ls;
  __syncthreads();
  for (int s = 128; s; s >>= 1) {
    if (tid < s) red[tid] += red[tid + s];
    __syncthreads();
  }
  if (tid == 0) atomicAdd(loss_ws, red[0]);
}

__global__ void vq_final(const int* __restrict__ hist, const double* __restrict__ loss_ws,
                         float* __restrict__ out) {
  __shared__ float red[512];
  const int t = threadIdx.x;
  const float p = (float)hist[t] * (1.0f / (float)N_ROWS);
  red[t] = p * logf(p + 1e-10f);
  __syncthreads();
  for (int s = 256; s; s >>= 1) {
    if (t < s) red[t] += red[t + s];
    __syncthreads();
  }
  if (t == 0) {
    out[OFF_PERP] = expf(-red[0]);
    const float m = (float)(*loss_ws / (double)Q_ELEMS);
    out[OFF_LOSS] = m + 0.25f * m;
  }
}

extern "C" void kernel_launch(void* const* d_in, const int* in_sizes, int n_in,
                              void* d_out, int out_size, void* d_ws, size_t ws_size,
                              hipStream_t stream) {
  (void)in_sizes; (void)n_in; (void)out_size; (void)ws_size;
  float* in    = (float*)d_in[0];
  const float* embed = (const float*)d_in[1];
  float* out = (float*)d_out;

  double* loss_ws = (double*)d_ws;
  int*    hist    = (int*)((char*)d_ws + 16);
  float*  esq     = (float*)((char*)d_ws + 4096);

  vq_init<<<1, 512, 0, stream>>>(embed, loss_ws, hist, esq, out + OFF_EMBED);
  vq_gemm<<<(N_ROWS / RPB) * 2, TPB, 0, stream>>>(in, embed, esq, out);
  vq_epilogue<<<N_ROWS / 256, 256, 0, stream>>>(in, embed, hist, loss_ws, out);
  vq_final<<<1, 512, 0, stream>>>(hist, loss_ws, out);
}

// Round 10
// 272.299 us; speedup vs baseline: 8.7649x; 8.7649x over previous
//
#include <hip/hip_runtime.h>
#include <math.h>
#include <float.h>

// Problem constants (B,C,L,K) = (32, 64, 4096, 512)
#define B_DIM 32
#define C_DIM 64
#define L_DIM 4096
#define K_CB  512
#define N_ROWS (B_DIM * L_DIM)            // 131072
#define Q_ELEMS (B_DIM * C_DIM * L_DIM)   // 8388608

#define OFF_LOSS  0
#define OFF_Q     1
#define OFF_PERP  (1 + Q_ELEMS)
#define OFF_EMBED (OFF_PERP + 1)
#define OFF_IDX   (OFF_EMBED + K_CB * C_DIM)
#define OFF_ENC   (OFF_IDX + N_ROWS)

#define MARGIN 1.25e-4f   // >> 2*(1e-7 dot bound + ulp(64)); ~2% rows flagged

using f4    = __attribute__((ext_vector_type(4))) float;
using f2    = __attribute__((ext_vector_type(2))) float;
using f32x4 = __attribute__((ext_vector_type(4))) float;
using s16x8 = __attribute__((ext_vector_type(8))) short;

// bf16 RN-even convert via bit ops (exact residual splits)
__device__ __forceinline__ unsigned cvt_bf16_bits(float v) {
  unsigned u = __float_as_uint(v);
  return (u + 0x7FFFu + ((u >> 16) & 1u)) >> 16;
}
__device__ __forceinline__ float bf16_to_f(unsigned h) {
  return __uint_as_float(h << 16);
}

// ws layout: [0:8) double loss; [16:16+2048) int hist[512]; [4096:+2048) float esq[512]

__global__ void vq_init(const float* __restrict__ embed,
                        double* __restrict__ loss_ws,
                        int* __restrict__ hist,
                        float* __restrict__ esq,
                        float* __restrict__ out_embed) {
  const int t = threadIdx.x;  // 512 threads, 1 block
  if (t == 0) *loss_ws = 0.0;
  hist[t] = 0;
  const float* row = embed + (size_t)t * C_DIM;
  float s = 0.f;
#pragma unroll
  for (int c = 0; c < C_DIM; ++c) s = fmaf(row[c], row[c], s);  // chain, matches recipe
  esq[t] = s;
#pragma unroll
  for (int i = 0; i < K_CB * C_DIM / 512; ++i)
    out_embed[i * 512 + t] = embed[i * 512 + t];
}

// ---------------------------------------------------------------------------
// MFMA distance + top-2 filter. Block: 256 thr (4 waves), 128 rows.
// x,e split into 3 bf16 (hi/mid/lo); dot = 6 MFMA cross-terms, fp32-accurate
// to ~1e-7. Rows whose top-2 gap <= MARGIN are flagged (idx = 1024+k) for
// exact re-scan. Also zero-fills the whole enc matrix (overlapped nt stores).
// Fragment maps (16x16x32 bf16): A row=lane&15,k=(lane>>4)*8+j; B col=lane&15,
// same k; D col=lane&15,row=(lane>>4)*4+reg [m89]. K-order cancels (same for
// A and B -> permutation-invariant dot).
// ---------------------------------------------------------------------------
__global__ __launch_bounds__(256) void vq_mfma(
    const float* __restrict__ in, const float* __restrict__ embed,
    const float* __restrict__ esq_g, float* __restrict__ out) {
  __shared__ __align__(16) unsigned short frag[3 * 8192];  // 48 KB, x-frags then e-chunks
  __shared__ float esq_s[K_CB];
  __shared__ float fs_s[128];

  const int tid = threadIdx.x;
  const int w   = tid >> 6;      // wave 0..3 -> row groups 2w, 2w+1
  const int ln  = tid & 63;
  const int blk = blockIdx.x;    // 1024 blocks
  const int R0  = blk * 128;     // flat row base
  const int b   = R0 >> 12;
  const int l0  = R0 & (L_DIM - 1);

  // --- phase 1a: build x fragments (3 splits) ---
  // quad q: G=q>>7, s=(q>>6)&1, o=(q>>4)&3, m=q&15 ; row=16G+m, c=32s+8o+j
#pragma unroll
  for (int qq = 0; qq < 4; ++qq) {
    const int q = qq * 256 + tid;
    const int G = q >> 7, s = (q >> 6) & 1, l5 = q & 63;
    const int o = l5 >> 4, m = l5 & 15;
    const int row = 16 * G + m;
    const int cb = 32 * s + 8 * o;
    const float* xp = in + (size_t)b * (C_DIM * L_DIM) + l0 + row;
    s16x8 ph, pm, pl;
#pragma unroll
    for (int j = 0; j < 8; ++j) {
      const float v = xp[(size_t)(cb + j) * L_DIM];
      const unsigned hu = cvt_bf16_bits(v);
      const float r1 = v - bf16_to_f(hu);
      const unsigned mu = cvt_bf16_bits(r1);
      const float r2 = r1 - bf16_to_f(mu);
      const unsigned lu = cvt_bf16_bits(r2);
      ph[j] = (short)hu; pm[j] = (short)mu; pl[j] = (short)lu;
    }
    const int slot = (G * 2 + s) * 64 + l5;
    *(s16x8*)&frag[0 * 8192 + slot * 8] = ph;
    *(s16x8*)&frag[1 * 8192 + slot * 8] = pm;
    *(s16x8*)&frag[2 * 8192 + slot * 8] = pl;
  }
  // --- phase 1b: fs chain per row (exact recipe) + esq stage ---
  if (tid < 128) {
    const float* xp = in + (size_t)b * (C_DIM * L_DIM) + l0 + tid;
    float s = 0.f;
#pragma unroll
    for (int c = 0; c < C_DIM; ++c) { const float v = xp[(size_t)c * L_DIM]; s = fmaf(v, v, s); }
    fs_s[tid] = s;
  }
  esq_s[tid] = esq_g[tid];
  esq_s[tid + 256] = esq_g[tid + 256];
  __syncthreads();

  // --- phase 2: load A-frags (persistent VGPRs) + per-lane fs ---
  s16x8 xa[2][2][3];   // [group][s][split]
#pragma unroll
  for (int g = 0; g < 2; ++g)
#pragma unroll
    for (int s = 0; s < 2; ++s)
#pragma unroll
      for (int sp = 0; sp < 3; ++sp)
        xa[g][s][sp] = *(const s16x8*)&frag[sp * 8192 + (((2 * w + g) * 2 + s) * 64 + ln) * 8];
  float fspl[2][4];
#pragma unroll
  for (int g = 0; g < 2; ++g)
#pragma unroll
    for (int r = 0; r < 4; ++r)
      fspl[g][r] = fs_s[(2 * w + g) * 16 + (ln >> 4) * 4 + r];

  float d1[2][4], d2[2][4];
  int   k1[2][4];
#pragma unroll
  for (int g = 0; g < 2; ++g)
#pragma unroll
    for (int r = 0; r < 4; ++r) { d1[g][r] = FLT_MAX; d2[g][r] = FLT_MAX; k1[g][r] = 0; }

  f2* encb = (f2*)(out + OFF_ENC) + (size_t)R0 * (K_CB / 2);
  f2 zz; zz.x = 0.f; zz.y = 0.f;

  // --- phase 3: K chunks (4 x 128 cw) ---
  for (int ck = 0; ck < 4; ++ck) {
    __syncthreads();  // A-frag reads / previous tiles done -> buffer reusable
    // build e-chunk fragments (3 splits) for cw [ck*128, ck*128+128)
#pragma unroll
    for (int qq = 0; qq < 4; ++qq) {
      const int q = qq * 256 + tid;
      const int tl = q >> 7, s = (q >> 6) & 1, l5 = q & 63;
      const int o = l5 >> 4, m = l5 & 15;
      const int cw = ck * 128 + 16 * tl + m;
      const int cb = 32 * s + 8 * o;
      const f4 va = *(const f4*)(embed + (size_t)cw * C_DIM + cb);
      const f4 vb = *(const f4*)(embed + (size_t)cw * C_DIM + cb + 4);
      s16x8 ph, pm, pl;
#pragma unroll
      for (int j = 0; j < 8; ++j) {
        const float v = (j < 4) ? va[j & 3] : vb[j & 3];
        const unsigned hu = cvt_bf16_bits(v);
        const float r1 = v - bf16_to_f(hu);
        const unsigned mu = cvt_bf16_bits(r1);
        const float r2 = r1 - bf16_to_f(mu);
        const unsigned lu = cvt_bf16_bits(r2);
        ph[j] = (short)hu; pm[j] = (short)mu; pl[j] = (short)lu;
      }
      const int slot = (tl * 2 + s) * 64 + l5;
      *(s16x8*)&frag[0 * 8192 + slot * 8] = ph;
      *(s16x8*)&frag[1 * 8192 + slot * 8] = pm;
      *(s16x8*)&frag[2 * 8192 + slot * 8] = pl;
    }
    __syncthreads();

#pragma unroll
    for (int tl = 0; tl < 8; ++tl) {
      s16x8 eb[2][3];
#pragma unroll
      for (int s = 0; s < 2; ++s)
#pragma unroll
        for (int sp = 0; sp < 3; ++sp)
          eb[s][sp] = *(const s16x8*)&frag[sp * 8192 + ((tl * 2 + s) * 64 + ln) * 8];
      const int kcol = ck * 128 + tl * 16 + (ln & 15);
      const float esql = esq_s[kcol];

      f32x4 aA0 = {0.f, 0.f, 0.f, 0.f}, aB0 = {0.f, 0.f, 0.f, 0.f};
      f32x4 aA1 = {0.f, 0.f, 0.f, 0.f}, aB1 = {0.f, 0.f, 0.f, 0.f};
      // 6 cross-terms (hi=0, mid=1, lo=2): hh, hm, mh, hl, lh, mm
#define TERM(ta, tb) \
      aA0 = __builtin_amdgcn_mfma_f32_16x16x32_bf16(xa[0][0][ta], eb[0][tb], aA0, 0, 0, 0); \
      aA1 = __builtin_amdgcn_mfma_f32_16x16x32_bf16(xa[1][0][ta], eb[0][tb], aA1, 0, 0, 0); \
      aB0 = __builtin_amdgcn_mfma_f32_16x16x32_bf16(xa[0][1][ta], eb[1][tb], aB0, 0, 0, 0); \
      aB1 = __builtin_amdgcn_mfma_f32_16x16x32_bf16(xa[1][1][ta], eb[1][tb], aB1, 0, 0, 0);
      TERM(0, 0) TERM(0, 1) TERM(1, 0) TERM(0, 2) TERM(2, 0) TERM(1, 1)
#undef TERM

      // d = fl(fl(fs+esq) - 2*dot)  (same formula shape as exact recipe)
#pragma unroll
      for (int r = 0; r < 4; ++r) {
        const float dd0 = fmaf(-2.0f, aA0[r] + aB0[r], fspl[0][r] + esql);
        const bool c0 = dd0 < d1[0][r];
        d2[0][r] = c0 ? d1[0][r] : fminf(d2[0][r], dd0);
        d1[0][r] = c0 ? dd0 : d1[0][r];
        k1[0][r] = c0 ? kcol : k1[0][r];
        const float dd1 = fmaf(-2.0f, aA1[r] + aB1[r], fspl[1][r] + esql);
        const bool c1 = dd1 < d1[1][r];
        d2[1][r] = c1 ? d1[1][r] : fminf(d2[1][r], dd1);
        d1[1][r] = c1 ? dd1 : d1[1][r];
        k1[1][r] = c1 ? kcol : k1[1][r];
      }

      // enc zero-fill: 4 coalesced f2 nt-stores per thread per tile
      {
        const int ti = ck * 8 + tl;  // 0..31
#pragma unroll
        for (int it = 0; it < 4; ++it)
          __builtin_nontemporal_store(zz, encb + (size_t)ti * 1024 + it * 256 + tid);
      }
    }
  }

  // --- phase 4: cross-lane top-2 merge over the 16 cols (lex on ties) ---
#pragma unroll
  for (int off = 1; off < 16; off <<= 1) {
#pragma unroll
    for (int g = 0; g < 2; ++g)
#pragma unroll
      for (int r = 0; r < 4; ++r) {
        const float od1 = __shfl_xor(d1[g][r], off);
        const int   ok1 = __shfl_xor(k1[g][r], off);
        const float od2 = __shfl_xor(d2[g][r], off);
        const bool take = (od1 < d1[g][r]) || (od1 == d1[g][r] && ok1 < k1[g][r]);
        const float nd2 = take ? fminf(d1[g][r], od2) : fminf(od1, d2[g][r]);
        d1[g][r] = take ? od1 : d1[g][r];
        k1[g][r] = take ? ok1 : k1[g][r];
        d2[g][r] = nd2;
      }
  }

  // --- phase 5: write idx (flag uncertain rows with +1024) ---
  if ((ln & 15) == 0) {
#pragma unroll
    for (int g = 0; g < 2; ++g)
#pragma unroll
      for (int r = 0; r < 4; ++r) {
        const int n = R0 + (2 * w + g) * 16 + (ln >> 4) * 4 + r;
        const bool unc = d2[g][r] <= d1[g][r] + MARGIN;
        out[OFF_IDX + n] = (float)(k1[g][r] + (unc ? 1024 : 0));
      }
  }
}

// ---------------------------------------------------------------------------
// Exact re-scan of flagged rows (bit-identical chain recipe of R1-R8).
// One wave per 64 rows; whole wave cooperates per flagged row.
// ---------------------------------------------------------------------------
__global__ __launch_bounds__(256) void vq_fix(
    const float* __restrict__ in, const float* __restrict__ embed,
    const float* __restrict__ esq_g, float* __restrict__ out) {
  const int w = threadIdx.x >> 6, ln = threadIdx.x & 63;
  const int r0 = (blockIdx.x * 4 + w) * 64;
  const float iv = out[OFF_IDX + r0 + ln];
  unsigned long long mask = __ballot(iv >= 1024.0f);
  while (mask) {
    const int bit = __ffsll((unsigned long long)mask) - 1;
    mask &= mask - 1;
    const int row = r0 + bit, b = row >> 12, l = row & (L_DIM - 1);
    const float* xp = in + (size_t)b * (C_DIM * L_DIM) + l;
    float xr[C_DIM];
#pragma unroll
    for (int c = 0; c < C_DIM; ++c) xr[c] = xp[(size_t)c * L_DIM];  // broadcast
    float fs = 0.f;
#pragma unroll
    for (int c = 0; c < C_DIM; ++c) fs = fmaf(xr[c], xr[c], fs);
    float bd = FLT_MAX; int bk = 0;
#pragma unroll
    for (int kk = 0; kk < 8; ++kk) {
      const int k = ln * 8 + kk;                  // ascending within lane
      const float* ep = embed + (size_t)k * C_DIM;
      float a = 0.f;
#pragma unroll
      for (int c = 0; c < C_DIM; ++c) a = fmaf(xr[c], ep[c], a);  // exact chain
      const float d = fmaf(-2.0f, a, fs + esq_g[k]);
      if (d < bd) { bd = d; bk = k; }             // strict <
    }
#pragma unroll
    for (int off = 32; off; off >>= 1) {          // lex reduce -> first-min
      const float od = __shfl_xor(bd, off);
      const int   ok = __shfl_xor(bk, off);
      if (od < bd || (od == bd && ok < bk)) { bd = od; bk = ok; }
    }
    if (ln == 0) out[OFF_IDX + row] = (float)bk;
  }
}

// ---------------------------------------------------------------------------
// Epilogue: hist + one-hot + quantized_st + loss (idx is final here).
// ---------------------------------------------------------------------------
__global__ __launch_bounds__(256) void vq_epi(
    const float* __restrict__ in, const float* __restrict__ embed,
    int* __restrict__ hist, double* __restrict__ loss_ws,
    float* __restrict__ out) {
  __shared__ double red[256];
  const int tid = threadIdx.x;
  const int r = blockIdx.x * 256 + tid;
  const int b = r >> 12;
  const int l = r & (L_DIM - 1);

  const int k = (int)out[OFF_IDX + r];
  atomicAdd(&hist[k], 1);
  out[OFF_ENC + (size_t)r * K_CB + k] = 1.0f;   // enc already zeroed by vq_mfma

  const float* ep = embed + (size_t)k * C_DIM;
  const float* xp = in + (size_t)b * (C_DIM * L_DIM) + l;
  float* qp = out + OFF_Q + (size_t)b * (C_DIM * L_DIM) + l;
  double ls = 0.0;
#pragma unroll
  for (int c = 0; c < C_DIM; ++c) {
    const float xv = xp[(size_t)c * L_DIM];
    const float d = ep[c] - xv;
    __builtin_nontemporal_store(xv + d, qp + (size_t)c * L_DIM);
    ls += (double)(d * d);
  }

  red[tid] = ls;
  __syncthreads();
  for (int s = 128; s; s >>= 1) {
    if (tid < s) red[tid] += red[tid + s];
    __syncthreads();
  }
  if (tid == 0) atomicAdd(loss_ws, red[0]);
}

__global__ void vq_final(const int* __restrict__ hist, const double* __restrict__ loss_ws,
                         float* __restrict__ out) {
  __shared__ float red[512];
  const int t = threadIdx.x;
  const float p = (float)hist[t] * (1.0f / (float)N_ROWS);
  red[t] = p * logf(p + 1e-10f);
  __syncthreads();
  for (int s = 256; s; s >>= 1) {
    if (t < s) red[t] += red[t + s];
    __syncthreads();
  }
  if (t == 0) {
    out[OFF_PERP] = expf(-red[0]);
    const float m = (float)(*loss_ws / (double)Q_ELEMS);
    out[OFF_LOSS] = m + 0.25f * m;
  }
}

extern "C" void kernel_launch(void* const* d_in, const int* in_sizes, int n_in,
                              void* d_out, int out_size, void* d_ws, size_t ws_size,
                              hipStream_t stream) {
  (void)in_sizes; (void)n_in; (void)out_size; (void)ws_size;
  const float* in    = (const float*)d_in[0];
  const float* embed = (const float*)d_in[1];
  float* out = (float*)d_out;

  double* loss_ws = (double*)d_ws;
  int*    hist    = (int*)((char*)d_ws + 16);
  float*  esq     = (float*)((char*)d_ws + 4096);

  vq_init<<<1, 512, 0, stream>>>(embed, loss_ws, hist, esq, out + OFF_EMBED);
  vq_mfma<<<N_ROWS / 128, 256, 0, stream>>>(in, embed, esq, out);
  vq_fix<<<N_ROWS / 256, 256, 0, stream>>>(in, embed, esq, out);
  vq_epi<<<N_ROWS / 256, 256, 0, stream>>>(in, embed, hist, loss_ws, out);
  vq_final<<<1, 512, 0, stream>>>(hist, loss_ws, out);
}

// Round 11
// 219.313 us; speedup vs baseline: 10.8825x; 1.2416x over previous
//
#include <hip/hip_runtime.h>
#include <math.h>
#include <float.h>

// Problem constants (B,C,L,K) = (32, 64, 4096, 512)
#define B_DIM 32
#define C_DIM 64
#define L_DIM 4096
#define K_CB  512
#define N_ROWS (B_DIM * L_DIM)            // 131072
#define Q_ELEMS (B_DIM * C_DIM * L_DIM)   // 8388608

#define OFF_LOSS  0
#define OFF_Q     1
#define OFF_PERP  (1 + Q_ELEMS)
#define OFF_EMBED (OFF_PERP + 1)
#define OFF_IDX   (OFF_EMBED + K_CB * C_DIM)
#define OFF_ENC   (OFF_IDX + N_ROWS)

#define MARGIN 1.25e-4f   // verified R10; >> 2*(2-split dot err ~1e-5)

using f4    = __attribute__((ext_vector_type(4))) float;
using f2    = __attribute__((ext_vector_type(2))) float;
using f32x4 = __attribute__((ext_vector_type(4))) float;
using s16x8 = __attribute__((ext_vector_type(8))) short;

// exact bf16 RN-even split helpers (residuals exactly representable in fp32)
__device__ __forceinline__ unsigned cvt_bf16_bits(float v) {
  unsigned u = __float_as_uint(v);
  return (u + 0x7FFFu + ((u >> 16) & 1u)) >> 16;
}
__device__ __forceinline__ float bf16_to_f(unsigned h) {
  return __uint_as_float(h << 16);
}

// ws layout: [0:8) double loss; [16:16+2048) int hist[512]; [4096:+2048) float esq[512]

__global__ void vq_init(const float* __restrict__ embed,
                        double* __restrict__ loss_ws,
                        int* __restrict__ hist,
                        float* __restrict__ esq,
                        float* __restrict__ out_embed) {
  const int t = threadIdx.x;  // 512 threads, 1 block
  if (t == 0) *loss_ws = 0.0;
  hist[t] = 0;
  const float* row = embed + (size_t)t * C_DIM;
  float s = 0.f;
#pragma unroll
  for (int c = 0; c < C_DIM; ++c) s = fmaf(row[c], row[c], s);  // exact chain
  esq[t] = s;
#pragma unroll
  for (int i = 0; i < K_CB * C_DIM / 512; ++i)
    out_embed[i * 512 + t] = embed[i * 512 + t];
}

// ---------------------------------------------------------------------------
// Fully-fused VQ via MFMA (2-split hi/mid, 4 cross-terms) + exact rescue.
// Block: 256 thr (4 waves), 128 rows. Verified components carried over:
//  - fragment maps + margin/top-2 logic (R10, absmax 0)
//  - exact-chain rescan with lex first-min (R10 vq_fix)
//  - enc zero-fill overlap + vmcnt(0)+barrier one-hot ordering (R8/R9)
//  - swizzled eSel quantize epilogue (R4)
// ---------------------------------------------------------------------------
__global__ __launch_bounds__(256) void vq_fused(
    const float* __restrict__ in, const float* __restrict__ embed,
    const float* __restrict__ esq_g, int* __restrict__ hist,
    double* __restrict__ loss_ws, float* __restrict__ out) {
  // 32KB x-fragments; later reused: eSel f32[64][64] (16KB) @A0, xrow/red @A1
  __shared__ __align__(16) char smemA0[16384];
  __shared__ __align__(16) char smemA1[16384];
  __shared__ __align__(16) char smemE[16384];   // e-chunk fragments (2 splits x 8KB)
  __shared__ float esq_s[K_CB];
  __shared__ float fs_s[128];
  __shared__ int   k_s[128];

  unsigned short* xfr0 = (unsigned short*)smemA0;
  unsigned short* xfr1 = (unsigned short*)smemA1;
  unsigned short* efr0 = (unsigned short*)smemE;
  unsigned short* efr1 = (unsigned short*)(smemE + 8192);

  const int tid = threadIdx.x;
  const int w   = tid >> 6;
  const int ln  = tid & 63;
  const int blk = blockIdx.x;    // 1024 blocks
  const int R0  = blk * 128;
  const int b   = R0 >> 12;
  const int l0  = R0 & (L_DIM - 1);

  // --- phase 1a: x fragments, 2 exact splits ---
#pragma unroll
  for (int qq = 0; qq < 4; ++qq) {
    const int q = qq * 256 + tid;          // 0..1023
    const int G = q >> 7, s = (q >> 6) & 1, l5 = q & 63;
    const int o = l5 >> 4, m = l5 & 15;
    const int row = 16 * G + m;
    const int cb = 32 * s + 8 * o;
    const float* xp = in + (size_t)b * (C_DIM * L_DIM) + l0 + row;
    s16x8 ph, pm;
#pragma unroll
    for (int j = 0; j < 8; ++j) {
      const float v = xp[(size_t)(cb + j) * L_DIM];
      const unsigned hu = cvt_bf16_bits(v);
      const float r1 = v - bf16_to_f(hu);     // exact residual
      const unsigned mu = cvt_bf16_bits(r1);
      ph[j] = (short)hu; pm[j] = (short)mu;
    }
    const int slot = (G * 2 + s) * 64 + l5;
    *(s16x8*)&xfr0[slot * 8] = ph;
    *(s16x8*)&xfr1[slot * 8] = pm;
  }
  // --- phase 1b: exact fs chain per row (also reused by rescan) ---
  if (tid < 128) {
    const float* xp = in + (size_t)b * (C_DIM * L_DIM) + l0 + tid;
    float s = 0.f;
#pragma unroll
    for (int c = 0; c < C_DIM; ++c) { const float v = xp[(size_t)c * L_DIM]; s = fmaf(v, v, s); }
    fs_s[tid] = s;
  }
  esq_s[tid] = esq_g[tid];
  esq_s[tid + 256] = esq_g[tid + 256];
  __syncthreads();

  // --- phase 2: persistent A-fragments + fs slices ---
  s16x8 xa[2][2][2];   // [row-group g][c-half s][split]
#pragma unroll
  for (int g = 0; g < 2; ++g)
#pragma unroll
    for (int s = 0; s < 2; ++s) {
      const int slot = (((2 * w + g) * 2 + s) * 64 + ln) * 8;
      xa[g][s][0] = *(const s16x8*)&xfr0[slot];
      xa[g][s][1] = *(const s16x8*)&xfr1[slot];
    }
  float fspl[2][4];
#pragma unroll
  for (int g = 0; g < 2; ++g)
#pragma unroll
    for (int r = 0; r < 4; ++r)
      fspl[g][r] = fs_s[(2 * w + g) * 16 + (ln >> 4) * 4 + r];

  float d1[2][4], d2[2][4];
  int   k1[2][4];
#pragma unroll
  for (int g = 0; g < 2; ++g)
#pragma unroll
    for (int r = 0; r < 4; ++r) { d1[g][r] = FLT_MAX; d2[g][r] = FLT_MAX; k1[g][r] = 0; }

  f2* encb = (f2*)(out + OFF_ENC) + (size_t)R0 * (K_CB / 2);
  f2 zz; zz.x = 0.f; zz.y = 0.f;

  // --- phase 3: 8 chunks x 64 codewords ---
  for (int ck = 0; ck < 8; ++ck) {
    const int k0 = ck * 64;
    __syncthreads();   // previous chunk's fragment reads done
#pragma unroll
    for (int qq = 0; qq < 2; ++qq) {
      const int q = qq * 256 + tid;        // 0..511
      const int tl = q >> 7, s = (q >> 6) & 1, l5 = q & 63;
      const int o = l5 >> 4, m = l5 & 15;
      const int cw = k0 + 16 * tl + m;
      const int cb = 32 * s + 8 * o;
      const f4 va = *(const f4*)(embed + (size_t)cw * C_DIM + cb);
      const f4 vb = *(const f4*)(embed + (size_t)cw * C_DIM + cb + 4);
      s16x8 ph, pm;
#pragma unroll
      for (int j = 0; j < 8; ++j) {
        const float v = (j < 4) ? va[j & 3] : vb[j & 3];
        const unsigned hu = cvt_bf16_bits(v);
        const float r1 = v - bf16_to_f(hu);
        const unsigned mu = cvt_bf16_bits(r1);
        ph[j] = (short)hu; pm[j] = (short)mu;
      }
      const int slot = (tl * 2 + s) * 64 + l5;
      *(s16x8*)&efr0[slot * 8] = ph;
      *(s16x8*)&efr1[slot * 8] = pm;
    }
    __syncthreads();

#pragma unroll
    for (int tl = 0; tl < 4; ++tl) {
      s16x8 eb[2][2];   // [c-half s][split]
#pragma unroll
      for (int s = 0; s < 2; ++s) {
        const int slot = ((tl * 2 + s) * 64 + ln) * 8;
        eb[s][0] = *(const s16x8*)&efr0[slot];
        eb[s][1] = *(const s16x8*)&efr1[slot];
      }
      const int kcol = k0 + tl * 16 + (ln & 15);
      const float esql = esq_s[kcol];

      f32x4 aA0 = {0.f,0.f,0.f,0.f}, aB0 = {0.f,0.f,0.f,0.f};
      f32x4 aA1 = {0.f,0.f,0.f,0.f}, aB1 = {0.f,0.f,0.f,0.f};
      // 4 cross-terms: hh, hm, mh, mm (hi=0, mid=1)
#define TERM(ta, tb) \
      aA0 = __builtin_amdgcn_mfma_f32_16x16x32_bf16(xa[0][0][ta], eb[0][tb], aA0, 0, 0, 0); \
      aA1 = __builtin_amdgcn_mfma_f32_16x16x32_bf16(xa[1][0][ta], eb[0][tb], aA1, 0, 0, 0); \
      aB0 = __builtin_amdgcn_mfma_f32_16x16x32_bf16(xa[0][1][ta], eb[1][tb], aB0, 0, 0, 0); \
      aB1 = __builtin_amdgcn_mfma_f32_16x16x32_bf16(xa[1][1][ta], eb[1][tb], aB1, 0, 0, 0);
      TERM(0, 0) TERM(0, 1) TERM(1, 0) TERM(1, 1)
#undef TERM

#pragma unroll
      for (int r = 0; r < 4; ++r) {
        const float dd0 = fmaf(-2.0f, aA0[r] + aB0[r], fspl[0][r] + esql);
        const bool c0 = dd0 < d1[0][r];
        d2[0][r] = c0 ? d1[0][r] : fminf(d2[0][r], dd0);
        d1[0][r] = c0 ? dd0 : d1[0][r];
        k1[0][r] = c0 ? kcol : k1[0][r];
        const float dd1 = fmaf(-2.0f, aA1[r] + aB1[r], fspl[1][r] + esql);
        const bool c1 = dd1 < d1[1][r];
        d2[1][r] = c1 ? d1[1][r] : fminf(d2[1][r], dd1);
        d1[1][r] = c1 ? dd1 : d1[1][r];
        k1[1][r] = c1 ? kcol : k1[1][r];
      }

      // enc zero-fill: 4 coalesced f2 nt-stores / thread / tile (overlaps HBM)
      {
        const int ti = ck * 4 + tl;  // 0..31
#pragma unroll
        for (int it = 0; it < 4; ++it)
          __builtin_nontemporal_store(zz, encb + (size_t)ti * 1024 + it * 256 + tid);
      }
    }
  }

  // --- phase 4: cross-lane top-2 merge over 16 cols (lex on ties; R10-verified) ---
#pragma unroll
  for (int off = 1; off < 16; off <<= 1) {
#pragma unroll
    for (int g = 0; g < 2; ++g)
#pragma unroll
      for (int r = 0; r < 4; ++r) {
        const float od1 = __shfl_xor(d1[g][r], off);
        const int   ok1 = __shfl_xor(k1[g][r], off);
        const float od2 = __shfl_xor(d2[g][r], off);
        const bool take = (od1 < d1[g][r]) || (od1 == d1[g][r] && ok1 < k1[g][r]);
        const float nd2 = take ? fminf(d1[g][r], od2) : fminf(od1, d2[g][r]);
        d1[g][r] = take ? od1 : d1[g][r];
        k1[g][r] = take ? ok1 : k1[g][r];
        d2[g][r] = nd2;
      }
  }

  // --- phase 5: stash k (+flag bit 16 if uncertain) in LDS ---
  if ((ln & 15) == 0) {
#pragma unroll
    for (int g = 0; g < 2; ++g)
#pragma unroll
      for (int r = 0; r < 4; ++r) {
        const int row = (2 * w + g) * 16 + (ln >> 4) * 4 + r;
        const bool unc = d2[g][r] <= d1[g][r] + MARGIN;
        k_s[row] = k1[g][r] | (unc ? 0x10000 : 0);
      }
  }
  __syncthreads();

  // --- rescan flagged rows with the exact bit-identical chain (rare ~1%) ---
  {
    float* xrow = (float*)smemA1 + w * C_DIM;   // per-wave 64-float buffer
    unsigned long long mask = __ballot(ln < 32 && (k_s[32 * w + ln] & 0x10000));
    while (mask) {
      const int bit = __ffsll(mask) - 1;
      mask &= mask - 1;
      const int row = 32 * w + bit;
      xrow[ln] = in[(size_t)b * (C_DIM * L_DIM) + (size_t)ln * L_DIM + l0 + row];
      const float fs = fs_s[row];                // exact chain from phase 1b
      float bd = FLT_MAX; int bk = 0;
#pragma unroll
      for (int kk = 0; kk < 8; ++kk) {
        const int k = ln * 8 + kk;               // ascending per lane
        const f4* ep = (const f4*)(embed + (size_t)k * C_DIM);
        float a = 0.f;
#pragma unroll
        for (int cq = 0; cq < 16; ++cq) {
          const f4 e4 = ep[cq];
#pragma unroll
          for (int ii = 0; ii < 4; ++ii) a = fmaf(xrow[cq * 4 + ii], e4[ii], a);
        }
        const float d = fmaf(-2.0f, a, fs + esq_s[k]);
        if (d < bd) { bd = d; bk = k; }          // strict <
      }
#pragma unroll
      for (int off = 32; off; off >>= 1) {       // lex reduce -> first-min
        const float od = __shfl_xor(bd, off);
        const int   ok = __shfl_xor(bk, off);
        if (od < bd || (od == bd && ok < bk)) { bd = od; bk = ok; }
      }
      if (ln == 0) k_s[row] = bk;
    }
  }
  __syncthreads();

  // --- indices + histogram ---
  if (tid < 128) {
    const int k = k_s[tid];
    out[OFF_IDX + R0 + tid] = (float)k;
    atomicAdd(&hist[k], 1);
  }

  // --- one-hot after ALL zero-fill stores of this block (R8-verified) ---
  asm volatile("s_waitcnt vmcnt(0)" ::: "memory");
  __syncthreads();
  if (tid < 128)
    out[OFF_ENC + (size_t)(R0 + tid) * K_CB + k_s[tid]] = 1.0f;

  // --- quantized_st + loss: R4-verified swizzled eSel, 2 passes of 64 rows ---
  double ls = 0.0;
  {
    float* eSel = (float*)smemA0;               // 16KB (x-frags dead)
    float* qbase = out + OFF_Q + (size_t)b * (C_DIM * L_DIM) + l0;
#pragma unroll
    for (int pass = 0; pass < 2; ++pass) {
      const int r0p = pass * 64;
      __syncthreads();
#pragma unroll 4
      for (int it = 0; it < 16; ++it) {          // stage: coalesced per-row e reads
        const int r = it * 4 + w;
        const int kr = k_s[r0p + r];
        eSel[r * C_DIM + (ln ^ (r & 31))] = embed[(size_t)kr * C_DIM + ln];
      }
      __syncthreads();
#pragma unroll 4
      for (int it = 0; it < 16; ++it) {          // quant: coalesced stores
        const int c = it * 4 + w;                // wave-uniform
        const int r = ln;                        // lane-consecutive
        const float xx = in[(size_t)b * (C_DIM * L_DIM) + (size_t)c * L_DIM + l0 + r0p + r];
        const float q = eSel[r * C_DIM + (c ^ (r & 31))];   // 2-way bank (free)
        const float d = q - xx;
        __builtin_nontemporal_store(xx + d, qbase + (size_t)c * L_DIM + r0p + r);
        ls += (double)(d * d);
      }
    }
  }

  // --- loss block-reduce (double), buffer overlaid on smemA1 ---
  {
    double* red = (double*)smemA1;
    __syncthreads();
    red[tid] = ls;
    __syncthreads();
    for (int s = 128; s; s >>= 1) {
      if (tid < s) red[tid] += red[tid + s];
      __syncthreads();
    }
    if (tid == 0) atomicAdd(loss_ws, red[0]);
  }
}

__global__ void vq_final(const int* __restrict__ hist, const double* __restrict__ loss_ws,
                         float* __restrict__ out) {
  __shared__ float red[512];
  const int t = threadIdx.x;
  const float p = (float)hist[t] * (1.0f / (float)N_ROWS);
  red[t] = p * logf(p + 1e-10f);
  __syncthreads();
  for (int s = 256; s; s >>= 1) {
    if (t < s) red[t] += red[t + s];
    __syncthreads();
  }
  if (t == 0) {
    out[OFF_PERP] = expf(-red[0]);
    const float m = (float)(*loss_ws / (double)Q_ELEMS);
    out[OFF_LOSS] = m + 0.25f * m;
  }
}

extern "C" void kernel_launch(void* const* d_in, const int* in_sizes, int n_in,
                              void* d_out, int out_size, void* d_ws, size_t ws_size,
                              hipStream_t stream) {
  (void)in_sizes; (void)n_in; (void)out_size; (void)ws_size;
  const float* in    = (const float*)d_in[0];
  const float* embed = (const float*)d_in[1];
  float* out = (float*)d_out;

  double* loss_ws = (double*)d_ws;
  int*    hist    = (int*)((char*)d_ws + 16);
  float*  esq     = (float*)((char*)d_ws + 4096);

  vq_init<<<1, 512, 0, stream>>>(embed, loss_ws, hist, esq, out + OFF_EMBED);
  vq_fused<<<N_ROWS / 128, 256, 0, stream>>>(in, embed, esq, hist, loss_ws, out);
  vq_final<<<1, 512, 0, stream>>>(hist, loss_ws, out);
}

// Round 12
// 195.574 us; speedup vs baseline: 12.2034x; 1.1214x over previous
//
#include <hip/hip_runtime.h>
#include <math.h>
#include <float.h>

// Problem constants (B,C,L,K) = (32, 64, 4096, 512)
#define B_DIM 32
#define C_DIM 64
#define L_DIM 4096
#define K_CB  512
#define N_ROWS (B_DIM * L_DIM)            // 131072
#define Q_ELEMS (B_DIM * C_DIM * L_DIM)   // 8388608

#define OFF_LOSS  0
#define OFF_Q     1
#define OFF_PERP  (1 + Q_ELEMS)
#define OFF_EMBED (OFF_PERP + 1)
#define OFF_IDX   (OFF_EMBED + K_CB * C_DIM)
#define OFF_ENC   (OFF_IDX + N_ROWS)

#define MARGIN 1.25e-4f   // verified R10/R11 (absmax 0 both rounds)

// ws layout: [0:8) double loss; [16:2064) int hist[512]; [4096:6144) float esq[512];
//            [8192: 8192+131072) e-fragment table (hi 64KB | mid 64KB)
#define WS_EFRAG_OFF 8192
#define WS_NEEDED    (WS_EFRAG_OFF + 131072)

using f4    = __attribute__((ext_vector_type(4))) float;
using f2    = __attribute__((ext_vector_type(2))) float;
using f32x4 = __attribute__((ext_vector_type(4))) float;
using s16x8 = __attribute__((ext_vector_type(8))) short;

__device__ __forceinline__ unsigned cvt_bf16_bits(float v) {
  unsigned u = __float_as_uint(v);
  return (u + 0x7FFFu + ((u >> 16) & 1u)) >> 16;
}
__device__ __forceinline__ float bf16_to_f(unsigned h) {
  return __uint_as_float(h << 16);
}

__global__ void vq_init(const float* __restrict__ embed,
                        double* __restrict__ loss_ws,
                        int* __restrict__ hist,
                        float* __restrict__ esq,
                        float* __restrict__ out_embed) {
  const int t = threadIdx.x;  // 512 threads, 1 block
  if (t == 0) *loss_ws = 0.0;
  hist[t] = 0;
  const float* row = embed + (size_t)t * C_DIM;
  float s = 0.f;
#pragma unroll
  for (int c = 0; c < C_DIM; ++c) s = fmaf(row[c], row[c], s);  // exact chain
  esq[t] = s;
#pragma unroll
  for (int i = 0; i < K_CB * C_DIM / 512; ++i)
    out_embed[i * 512 + t] = embed[i * 512 + t];
}

// ---------------------------------------------------------------------------
// Build the global e-fragment table ONCE (hi/mid bf16 splits, B-frag layout).
// slot = (kt*2 + s)*64 + l5 ; cw = kt*16 + (l5&15) ; c = 32*s + 8*(l5>>4) + j
// (identical mapping to the verified R11 per-chunk build)
// ---------------------------------------------------------------------------
__global__ __launch_bounds__(512) void vq_einit(
    const float* __restrict__ embed, unsigned short* __restrict__ etab) {
  const int slot = blockIdx.x * 512 + threadIdx.x;   // 0..4095
  const int kt = slot >> 7, s = (slot >> 6) & 1, l5 = slot & 63;
  const int o = l5 >> 4, m = l5 & 15;
  const int cw = kt * 16 + m;
  const int cb = 32 * s + 8 * o;
  const f4 va = *(const f4*)(embed + (size_t)cw * C_DIM + cb);
  const f4 vb = *(const f4*)(embed + (size_t)cw * C_DIM + cb + 4);
  s16x8 ph, pm;
#pragma unroll
  for (int j = 0; j < 8; ++j) {
    const float v = (j < 4) ? va[j & 3] : vb[j & 3];
    const unsigned hu = cvt_bf16_bits(v);
    const float r1 = v - bf16_to_f(hu);
    const unsigned mu = cvt_bf16_bits(r1);
    ph[j] = (short)hu; pm[j] = (short)mu;
  }
  *(s16x8*)&etab[slot * 8] = ph;
  *(s16x8*)&etab[32768 + slot * 8] = pm;
}

// ---------------------------------------------------------------------------
// MFMA VQ, e-fragments from the global table: barrier-free 32-tile K loop
// with 1-tile prefetch. x-split, top-2/margin, rescan, enc ordering, eSel
// quantize and loss are verbatim from the verified R11 kernel.
// ---------------------------------------------------------------------------
__global__ __launch_bounds__(256) void vq_mf(
    const float* __restrict__ in, const float* __restrict__ embed,
    const float* __restrict__ esq_g, const unsigned short* __restrict__ efrag,
    int* __restrict__ hist, double* __restrict__ loss_ws,
    float* __restrict__ out) {
  __shared__ __align__(16) char smemA0[16384];   // x hi frags -> eSel
  __shared__ __align__(16) char smemA1[16384];   // x mid frags -> xrow/red
  __shared__ float esq_s[K_CB];
  __shared__ float fs_s[128];
  __shared__ int   k_s[128];

  unsigned short* xfr0 = (unsigned short*)smemA0;
  unsigned short* xfr1 = (unsigned short*)smemA1;

  const int tid = threadIdx.x;
  const int w   = tid >> 6;
  const int ln  = tid & 63;
  const int blk = blockIdx.x;    // 1024 blocks
  const int R0  = blk * 128;
  const int b   = R0 >> 12;
  const int l0  = R0 & (L_DIM - 1);

  // --- phase 1a: x fragments, 2 exact splits (R11-verified) ---
#pragma unroll
  for (int qq = 0; qq < 4; ++qq) {
    const int q = qq * 256 + tid;          // 0..1023
    const int G = q >> 7, s = (q >> 6) & 1, l5 = q & 63;
    const int o = l5 >> 4, m = l5 & 15;
    const int row = 16 * G + m;
    const int cb = 32 * s + 8 * o;
    const float* xp = in + (size_t)b * (C_DIM * L_DIM) + l0 + row;
    s16x8 ph, pm;
#pragma unroll
    for (int j = 0; j < 8; ++j) {
      const float v = xp[(size_t)(cb + j) * L_DIM];
      const unsigned hu = cvt_bf16_bits(v);
      const float r1 = v - bf16_to_f(hu);
      const unsigned mu = cvt_bf16_bits(r1);
      ph[j] = (short)hu; pm[j] = (short)mu;
    }
    const int slot = (G * 2 + s) * 64 + l5;
    *(s16x8*)&xfr0[slot * 8] = ph;
    *(s16x8*)&xfr1[slot * 8] = pm;
  }
  // --- phase 1b: exact fs chain per row ---
  if (tid < 128) {
    const float* xp = in + (size_t)b * (C_DIM * L_DIM) + l0 + tid;
    float s = 0.f;
#pragma unroll
    for (int c = 0; c < C_DIM; ++c) { const float v = xp[(size_t)c * L_DIM]; s = fmaf(v, v, s); }
    fs_s[tid] = s;
  }
  esq_s[tid] = esq_g[tid];
  esq_s[tid + 256] = esq_g[tid + 256];
  __syncthreads();

  // --- phase 2: persistent A-fragments + fs slices ---
  s16x8 xa[2][2][2];   // [row-group g][c-half s][split]
#pragma unroll
  for (int g = 0; g < 2; ++g)
#pragma unroll
    for (int s = 0; s < 2; ++s) {
      const int slot = (((2 * w + g) * 2 + s) * 64 + ln) * 8;
      xa[g][s][0] = *(const s16x8*)&xfr0[slot];
      xa[g][s][1] = *(const s16x8*)&xfr1[slot];
    }
  float fspl[2][4];
#pragma unroll
  for (int g = 0; g < 2; ++g)
#pragma unroll
    for (int r = 0; r < 4; ++r)
      fspl[g][r] = fs_s[(2 * w + g) * 16 + (ln >> 4) * 4 + r];

  float d1[2][4], d2[2][4];
  int   k1[2][4];
#pragma unroll
  for (int g = 0; g < 2; ++g)
#pragma unroll
    for (int r = 0; r < 4; ++r) { d1[g][r] = FLT_MAX; d2[g][r] = FLT_MAX; k1[g][r] = 0; }

  f2* encb = (f2*)(out + OFF_ENC) + (size_t)R0 * (K_CB / 2);
  f2 zz; zz.x = 0.f; zz.y = 0.f;

  // --- phase 3: barrier-free kt loop, prefetch depth 1 ---
  s16x8 ebc[2][2], ebn[2][2];
#pragma unroll
  for (int s = 0; s < 2; ++s)
#pragma unroll
    for (int sp = 0; sp < 2; ++sp)
      ebc[s][sp] = *(const s16x8*)&efrag[sp * 32768 + ((0 * 2 + s) * 64 + ln) * 8];

  for (int kt = 0; kt < 32; ++kt) {
    const int ktn = (kt < 31) ? kt + 1 : 31;
#pragma unroll
    for (int s = 0; s < 2; ++s)
#pragma unroll
      for (int sp = 0; sp < 2; ++sp)
        ebn[s][sp] = *(const s16x8*)&efrag[sp * 32768 + ((ktn * 2 + s) * 64 + ln) * 8];

    const int kcol = kt * 16 + (ln & 15);
    const float esql = esq_s[kcol];

    f32x4 aA0 = {0.f,0.f,0.f,0.f}, aB0 = {0.f,0.f,0.f,0.f};
    f32x4 aA1 = {0.f,0.f,0.f,0.f}, aB1 = {0.f,0.f,0.f,0.f};
    // 4 cross-terms: hh, hm, mh, mm
#define TERM(ta, tb) \
    aA0 = __builtin_amdgcn_mfma_f32_16x16x32_bf16(xa[0][0][ta], ebc[0][tb], aA0, 0, 0, 0); \
    aA1 = __builtin_amdgcn_mfma_f32_16x16x32_bf16(xa[1][0][ta], ebc[0][tb], aA1, 0, 0, 0); \
    aB0 = __builtin_amdgcn_mfma_f32_16x16x32_bf16(xa[0][1][ta], ebc[1][tb], aB0, 0, 0, 0); \
    aB1 = __builtin_amdgcn_mfma_f32_16x16x32_bf16(xa[1][1][ta], ebc[1][tb], aB1, 0, 0, 0);
    TERM(0, 0) TERM(0, 1) TERM(1, 0) TERM(1, 1)
#undef TERM

#pragma unroll
    for (int r = 0; r < 4; ++r) {
      const float dd0 = fmaf(-2.0f, aA0[r] + aB0[r], fspl[0][r] + esql);
      const bool c0 = dd0 < d1[0][r];
      d2[0][r] = c0 ? d1[0][r] : fminf(d2[0][r], dd0);
      d1[0][r] = c0 ? dd0 : d1[0][r];
      k1[0][r] = c0 ? kcol : k1[0][r];
      const float dd1 = fmaf(-2.0f, aA1[r] + aB1[r], fspl[1][r] + esql);
      const bool c1 = dd1 < d1[1][r];
      d2[1][r] = c1 ? d1[1][r] : fminf(d2[1][r], dd1);
      d1[1][r] = c1 ? dd1 : d1[1][r];
      k1[1][r] = c1 ? kcol : k1[1][r];
    }

    // enc zero-fill: 4 coalesced f2 nt-stores / thread / tile (overlaps HBM)
#pragma unroll
    for (int it = 0; it < 4; ++it)
      __builtin_nontemporal_store(zz, encb + (size_t)kt * 1024 + it * 256 + tid);

#pragma unroll
    for (int s = 0; s < 2; ++s)
#pragma unroll
      for (int sp = 0; sp < 2; ++sp)
        ebc[s][sp] = ebn[s][sp];
  }

  // --- phase 4: cross-lane top-2 merge (R11-verified) ---
#pragma unroll
  for (int off = 1; off < 16; off <<= 1) {
#pragma unroll
    for (int g = 0; g < 2; ++g)
#pragma unroll
      for (int r = 0; r < 4; ++r) {
        const float od1 = __shfl_xor(d1[g][r], off);
        const int   ok1 = __shfl_xor(k1[g][r], off);
        const float od2 = __shfl_xor(d2[g][r], off);
        const bool take = (od1 < d1[g][r]) || (od1 == d1[g][r] && ok1 < k1[g][r]);
        const float nd2 = take ? fminf(d1[g][r], od2) : fminf(od1, d2[g][r]);
        d1[g][r] = take ? od1 : d1[g][r];
        k1[g][r] = take ? ok1 : k1[g][r];
        d2[g][r] = nd2;
      }
  }

  // --- phase 5: stash k (+flag bit 16 if uncertain) ---
  if ((ln & 15) == 0) {
#pragma unroll
    for (int g = 0; g < 2; ++g)
#pragma unroll
      for (int r = 0; r < 4; ++r) {
        const int row = (2 * w + g) * 16 + (ln >> 4) * 4 + r;
        const bool unc = d2[g][r] <= d1[g][r] + MARGIN;
        k_s[row] = k1[g][r] | (unc ? 0x10000 : 0);
      }
  }
  __syncthreads();

  // --- exact rescan of flagged rows (R11-verified) ---
  {
    float* xrow = (float*)smemA1 + w * C_DIM;
    unsigned long long mask = __ballot(ln < 32 && (k_s[32 * w + ln] & 0x10000));
    while (mask) {
      const int bit = __ffsll(mask) - 1;
      mask &= mask - 1;
      const int row = 32 * w + bit;
      xrow[ln] = in[(size_t)b * (C_DIM * L_DIM) + (size_t)ln * L_DIM + l0 + row];
      const float fs = fs_s[row];
      float bd = FLT_MAX; int bk = 0;
#pragma unroll
      for (int kk = 0; kk < 8; ++kk) {
        const int k = ln * 8 + kk;
        const f4* ep = (const f4*)(embed + (size_t)k * C_DIM);
        float a = 0.f;
#pragma unroll
        for (int cq = 0; cq < 16; ++cq) {
          const f4 e4 = ep[cq];
#pragma unroll
          for (int ii = 0; ii < 4; ++ii) a = fmaf(xrow[cq * 4 + ii], e4[ii], a);
        }
        const float d = fmaf(-2.0f, a, fs + esq_s[k]);
        if (d < bd) { bd = d; bk = k; }
      }
#pragma unroll
      for (int off = 32; off; off >>= 1) {
        const float od = __shfl_xor(bd, off);
        const int   ok = __shfl_xor(bk, off);
        if (od < bd || (od == bd && ok < bk)) { bd = od; bk = ok; }
      }
      if (ln == 0) k_s[row] = bk;
    }
  }
  __syncthreads();

  // --- indices + histogram ---
  if (tid < 128) {
    const int k = k_s[tid];
    out[OFF_IDX + R0 + tid] = (float)k;
    atomicAdd(&hist[k], 1);
  }

  // --- one-hot after ALL zero-fill stores of this block ---
  asm volatile("s_waitcnt vmcnt(0)" ::: "memory");
  __syncthreads();
  if (tid < 128)
    out[OFF_ENC + (size_t)(R0 + tid) * K_CB + k_s[tid]] = 1.0f;

  // --- quantized_st + loss: swizzled eSel, 2 passes (R11-verified) ---
  double ls = 0.0;
  {
    float* eSel = (float*)smemA0;
    float* qbase = out + OFF_Q + (size_t)b * (C_DIM * L_DIM) + l0;
#pragma unroll
    for (int pass = 0; pass < 2; ++pass) {
      const int r0p = pass * 64;
      __syncthreads();
#pragma unroll 4
      for (int it = 0; it < 16; ++it) {
        const int r = it * 4 + w;
        const int kr = k_s[r0p + r];
        eSel[r * C_DIM + (ln ^ (r & 31))] = embed[(size_t)kr * C_DIM + ln];
      }
      __syncthreads();
#pragma unroll 4
      for (int it = 0; it < 16; ++it) {
        const int c = it * 4 + w;
        const int r = ln;
        const float xx = in[(size_t)b * (C_DIM * L_DIM) + (size_t)c * L_DIM + l0 + r0p + r];
        const float q = eSel[r * C_DIM + (c ^ (r & 31))];
        const float d = q - xx;
        __builtin_nontemporal_store(xx + d, qbase + (size_t)c * L_DIM + r0p + r);
        ls += (double)(d * d);
      }
    }
  }

  {
    double* red = (double*)smemA1;
    __syncthreads();
    red[tid] = ls;
    __syncthreads();
    for (int s = 128; s; s >>= 1) {
      if (tid < s) red[tid] += red[tid + s];
      __syncthreads();
    }
    if (tid == 0) atomicAdd(loss_ws, red[0]);
  }
}

// ---------------------------------------------------------------------------
// Fallback (ws too small): verbatim R11 kernel (verified, 219 us total).
// ---------------------------------------------------------------------------
__global__ __launch_bounds__(256) void vq_fused_fb(
    const float* __restrict__ in, const float* __restrict__ embed,
    const float* __restrict__ esq_g, int* __restrict__ hist,
    double* __restrict__ loss_ws, float* __restrict__ out) {
  __shared__ __align__(16) char smemA0[16384];
  __shared__ __align__(16) char smemA1[16384];
  __shared__ __align__(16) char smemE[16384];
  __shared__ float esq_s[K_CB];
  __shared__ float fs_s[128];
  __shared__ int   k_s[128];

  unsigned short* xfr0 = (unsigned short*)smemA0;
  unsigned short* xfr1 = (unsigned short*)smemA1;
  unsigned short* efr0 = (unsigned short*)smemE;
  unsigned short* efr1 = (unsigned short*)(smemE + 8192);

  const int tid = threadIdx.x;
  const int w   = tid >> 6;
  const int ln  = tid & 63;
  const int blk = blockIdx.x;
  const int R0  = blk * 128;
  const int b   = R0 >> 12;
  const int l0  = R0 & (L_DIM - 1);

#pragma unroll
  for (int qq = 0; qq < 4; ++qq) {
    const int q = qq * 256 + tid;
    const int G = q >> 7, s = (q >> 6) & 1, l5 = q & 63;
    const int o = l5 >> 4, m = l5 & 15;
    const int row = 16 * G + m;
    const int cb = 32 * s + 8 * o;
    const float* xp = in + (size_t)b * (C_DIM * L_DIM) + l0 + row;
    s16x8 ph, pm;
#pragma unroll
    for (int j = 0; j < 8; ++j) {
      const float v = xp[(size_t)(cb + j) * L_DIM];
      const unsigned hu = cvt_bf16_bits(v);
      const float r1 = v - bf16_to_f(hu);
      const unsigned mu = cvt_bf16_bits(r1);
      ph[j] = (short)hu; pm[j] = (short)mu;
    }
    const int slot = (G * 2 + s) * 64 + l5;
    *(s16x8*)&xfr0[slot * 8] = ph;
    *(s16x8*)&xfr1[slot * 8] = pm;
  }
  if (tid < 128) {
    const float* xp = in + (size_t)b * (C_DIM * L_DIM) + l0 + tid;
    float s = 0.f;
#pragma unroll
    for (int c = 0; c < C_DIM; ++c) { const float v = xp[(size_t)c * L_DIM]; s = fmaf(v, v, s); }
    fs_s[tid] = s;
  }
  esq_s[tid] = esq_g[tid];
  esq_s[tid + 256] = esq_g[tid + 256];
  __syncthreads();

  s16x8 xa[2][2][2];
#pragma unroll
  for (int g = 0; g < 2; ++g)
#pragma unroll
    for (int s = 0; s < 2; ++s) {
      const int slot = (((2 * w + g) * 2 + s) * 64 + ln) * 8;
      xa[g][s][0] = *(const s16x8*)&xfr0[slot];
      xa[g][s][1] = *(const s16x8*)&xfr1[slot];
    }
  float fspl[2][4];
#pragma unroll
  for (int g = 0; g < 2; ++g)
#pragma unroll
    for (int r = 0; r < 4; ++r)
      fspl[g][r] = fs_s[(2 * w + g) * 16 + (ln >> 4) * 4 + r];

  float d1[2][4], d2[2][4];
  int   k1[2][4];
#pragma unroll
  for (int g = 0; g < 2; ++g)
#pragma unroll
    for (int r = 0; r < 4; ++r) { d1[g][r] = FLT_MAX; d2[g][r] = FLT_MAX; k1[g][r] = 0; }

  f2* encb = (f2*)(out + OFF_ENC) + (size_t)R0 * (K_CB / 2);
  f2 zz; zz.x = 0.f; zz.y = 0.f;

  for (int ck = 0; ck < 8; ++ck) {
    const int k0 = ck * 64;
    __syncthreads();
#pragma unroll
    for (int qq = 0; qq < 2; ++qq) {
      const int q = qq * 256 + tid;
      const int tl = q >> 7, s = (q >> 6) & 1, l5 = q & 63;
      const int o = l5 >> 4, m = l5 & 15;
      const int cw = k0 + 16 * tl + m;
      const int cb = 32 * s + 8 * o;
      const f4 va = *(const f4*)(embed + (size_t)cw * C_DIM + cb);
      const f4 vb = *(const f4*)(embed + (size_t)cw * C_DIM + cb + 4);
      s16x8 ph, pm;
#pragma unroll
      for (int j = 0; j < 8; ++j) {
        const float v = (j < 4) ? va[j & 3] : vb[j & 3];
        const unsigned hu = cvt_bf16_bits(v);
        const float r1 = v - bf16_to_f(hu);
        const unsigned mu = cvt_bf16_bits(r1);
        ph[j] = (short)hu; pm[j] = (short)mu;
      }
      const int slot = (tl * 2 + s) * 64 + l5;
      *(s16x8*)&efr0[slot * 8] = ph;
      *(s16x8*)&efr1[slot * 8] = pm;
    }
    __syncthreads();

#pragma unroll
    for (int tl = 0; tl < 4; ++tl) {
      s16x8 eb[2][2];
#pragma unroll
      for (int s = 0; s < 2; ++s) {
        const int slot = ((tl * 2 + s) * 64 + ln) * 8;
        eb[s][0] = *(const s16x8*)&efr0[slot];
        eb[s][1] = *(const s16x8*)&efr1[slot];
      }
      const int kcol = k0 + tl * 16 + (ln & 15);
      const float esql = esq_s[kcol];

      f32x4 aA0 = {0.f,0.f,0.f,0.f}, aB0 = {0.f,0.f,0.f,0.f};
      f32x4 aA1 = {0.f,0.f,0.f,0.f}, aB1 = {0.f,0.f,0.f,0.f};
#define TERM(ta, tb) \
      aA0 = __builtin_amdgcn_mfma_f32_16x16x32_bf16(xa[0][0][ta], eb[0][tb], aA0, 0, 0, 0); \
      aA1 = __builtin_amdgcn_mfma_f32_16x16x32_bf16(xa[1][0][ta], eb[0][tb], aA1, 0, 0, 0); \
      aB0 = __builtin_amdgcn_mfma_f32_16x16x32_bf16(xa[0][1][ta], eb[1][tb], aB0, 0, 0, 0); \
      aB1 = __builtin_amdgcn_mfma_f32_16x16x32_bf16(xa[1][1][ta], eb[1][tb], aB1, 0, 0, 0);
      TERM(0, 0) TERM(0, 1) TERM(1, 0) TERM(1, 1)
#undef TERM

#pragma unroll
      for (int r = 0; r < 4; ++r) {
        const float dd0 = fmaf(-2.0f, aA0[r] + aB0[r], fspl[0][r] + esql);
        const bool c0 = dd0 < d1[0][r];
        d2[0][r] = c0 ? d1[0][r] : fminf(d2[0][r], dd0);
        d1[0][r] = c0 ? dd0 : d1[0][r];
        k1[0][r] = c0 ? kcol : k1[0][r];
        const float dd1 = fmaf(-2.0f, aA1[r] + aB1[r], fspl[1][r] + esql);
        const bool c1 = dd1 < d1[1][r];
        d2[1][r] = c1 ? d1[1][r] : fminf(d2[1][r], dd1);
        d1[1][r] = c1 ? dd1 : d1[1][r];
        k1[1][r] = c1 ? kcol : k1[1][r];
      }
      {
        const int ti = ck * 4 + tl;
#pragma unroll
        for (int it = 0; it < 4; ++it)
          __builtin_nontemporal_store(zz, encb + (size_t)ti * 1024 + it * 256 + tid);
      }
    }
  }

#pragma unroll
  for (int off = 1; off < 16; off <<= 1) {
#pragma unroll
    for (int g = 0; g < 2; ++g)
#pragma unroll
      for (int r = 0; r < 4; ++r) {
        const float od1 = __shfl_xor(d1[g][r], off);
        const int   ok1 = __shfl_xor(k1[g][r], off);
        const float od2 = __shfl_xor(d2[g][r], off);
        const bool take = (od1 < d1[g][r]) || (od1 == d1[g][r] && ok1 < k1[g][r]);
        const float nd2 = take ? fminf(d1[g][r], od2) : fminf(od1, d2[g][r]);
        d1[g][r] = take ? od1 : d1[g][r];
        k1[g][r] = take ? ok1 : k1[g][r];
        d2[g][r] = nd2;
      }
  }

  if ((ln & 15) == 0) {
#pragma unroll
    for (int g = 0; g < 2; ++g)
#pragma unroll
      for (int r = 0; r < 4; ++r) {
        const int row = (2 * w + g) * 16 + (ln >> 4) * 4 + r;
        const bool unc = d2[g][r] <= d1[g][r] + MARGIN;
        k_s[row] = k1[g][r] | (unc ? 0x10000 : 0);
      }
  }
  __syncthreads();

  {
    float* xrow = (float*)smemA1 + w * C_DIM;
    unsigned long long mask = __ballot(ln < 32 && (k_s[32 * w + ln] & 0x10000));
    while (mask) {
      const int bit = __ffsll(mask) - 1;
      mask &= mask - 1;
      const int row = 32 * w + bit;
      xrow[ln] = in[(size_t)b * (C_DIM * L_DIM) + (size_t)ln * L_DIM + l0 + row];
      const float fs = fs_s[row];
      float bd = FLT_MAX; int bk = 0;
#pragma unroll
      for (int kk = 0; kk < 8; ++kk) {
        const int k = ln * 8 + kk;
        const f4* ep = (const f4*)(embed + (size_t)k * C_DIM);
        float a = 0.f;
#pragma unroll
        for (int cq = 0; cq < 16; ++cq) {
          const f4 e4 = ep[cq];
#pragma unroll
          for (int ii = 0; ii < 4; ++ii) a = fmaf(xrow[cq * 4 + ii], e4[ii], a);
        }
        const float d = fmaf(-2.0f, a, fs + esq_s[k]);
        if (d < bd) { bd = d; bk = k; }
      }
#pragma unroll
      for (int off = 32; off; off >>= 1) {
        const float od = __shfl_xor(bd, off);
        const int   ok = __shfl_xor(bk, off);
        if (od < bd || (od == bd && ok < bk)) { bd = od; bk = ok; }
      }
      if (ln == 0) k_s[row] = bk;
    }
  }
  __syncthreads();

  if (tid < 128) {
    const int k = k_s[tid];
    out[OFF_IDX + R0 + tid] = (float)k;
    atomicAdd(&hist[k], 1);
  }

  asm volatile("s_waitcnt vmcnt(0)" ::: "memory");
  __syncthreads();
  if (tid < 128)
    out[OFF_ENC + (size_t)(R0 + tid) * K_CB + k_s[tid]] = 1.0f;

  double ls = 0.0;
  {
    float* eSel = (float*)smemA0;
    float* qbase = out + OFF_Q + (size_t)b * (C_DIM * L_DIM) + l0;
#pragma unroll
    for (int pass = 0; pass < 2; ++pass) {
      const int r0p = pass * 64;
      __syncthreads();
#pragma unroll 4
      for (int it = 0; it < 16; ++it) {
        const int r = it * 4 + w;
        const int kr = k_s[r0p + r];
        eSel[r * C_DIM + (ln ^ (r & 31))] = embed[(size_t)kr * C_DIM + ln];
      }
      __syncthreads();
#pragma unroll 4
      for (int it = 0; it < 16; ++it) {
        const int c = it * 4 + w;
        const int r = ln;
        const float xx = in[(size_t)b * (C_DIM * L_DIM) + (size_t)c * L_DIM + l0 + r0p + r];
        const float q = eSel[r * C_DIM + (c ^ (r & 31))];
        const float d = q - xx;
        __builtin_nontemporal_store(xx + d, qbase + (size_t)c * L_DIM + r0p + r);
        ls += (double)(d * d);
      }
    }
  }

  {
    double* red = (double*)smemA1;
    __syncthreads();
    red[tid] = ls;
    __syncthreads();
    for (int s = 128; s; s >>= 1) {
      if (tid < s) red[tid] += red[tid + s];
      __syncthreads();
    }
    if (tid == 0) atomicAdd(loss_ws, red[0]);
  }
}

__global__ void vq_final(const int* __restrict__ hist, const double* __restrict__ loss_ws,
                         float* __restrict__ out) {
  __shared__ float red[512];
  const int t = threadIdx.x;
  const float p = (float)hist[t] * (1.0f / (float)N_ROWS);
  red[t] = p * logf(p + 1e-10f);
  __syncthreads();
  for (int s = 256; s; s >>= 1) {
    if (t < s) red[t] += red[t + s];
    __syncthreads();
  }
  if (t == 0) {
    out[OFF_PERP] = expf(-red[0]);
    const float m = (float)(*loss_ws / (double)Q_ELEMS);
    out[OFF_LOSS] = m + 0.25f * m;
  }
}

extern "C" void kernel_launch(void* const* d_in, const int* in_sizes, int n_in,
                              void* d_out, int out_size, void* d_ws, size_t ws_size,
                              hipStream_t stream) {
  (void)in_sizes; (void)n_in; (void)out_size;
  const float* in    = (const float*)d_in[0];
  const float* embed = (const float*)d_in[1];
  float* out = (float*)d_out;

  double* loss_ws = (double*)d_ws;
  int*    hist    = (int*)((char*)d_ws + 16);
  float*  esq     = (float*)((char*)d_ws + 4096);
  unsigned short* etab = (unsigned short*)((char*)d_ws + WS_EFRAG_OFF);

  vq_init<<<1, 512, 0, stream>>>(embed, loss_ws, hist, esq, out + OFF_EMBED);
  if (ws_size >= (size_t)WS_NEEDED) {
    vq_einit<<<8, 512, 0, stream>>>(embed, etab);
    vq_mf<<<N_ROWS / 128, 256, 0, stream>>>(in, embed, esq, etab, hist, loss_ws, out);
  } else {
    vq_fused_fb<<<N_ROWS / 128, 256, 0, stream>>>(in, embed, esq, hist, loss_ws, out);
  }
  vq_final<<<1, 512, 0, stream>>>(hist, loss_ws, out);
}